// Round 3
// baseline (2093.375 us; speedup 1.0000x reference)
//
#include <hip/hip_runtime.h>
#include <hip/hip_bf16.h>

// BeamDecoder: greedy CVRP-style decode.
// s_i(step) = c*( G[last,i] + (load/cap)*u_i )   (v==0 since bq==0; folded)
//
// R12: R11 (1396us) showed FETCH halved but VALUBusy 8%/CU -> still
// latency-bound; tier-1 cert rate is low because B1 = thr15 + lr*umax + 0.5
// uses the global worst-case |u| (3-sigma outlier) scaled by lr~1 at route
// starts. Fixes:
//  (1) CONVEX BOUND: t_j(lr) = g_j + lr*u_j is linear in lr in [0,1], so
//      max outside t <= (1-lr)*M0 + lr*M1 with M0 = thr (max outside g) and
//      M1 = max_{j not in list}(g_j + u_j), both per row from prep. Near-exact
//      -> cert succeeds whenever the true winner is in the top-15.
//  (2) Speculative tier-2 row load reinstated as PURE VMEM (per-lane
//      global_load_dwordx4 -> vmcnt; R10's poison was the SMEM thr load on
//      lgkmcnt). 3-deep rotation; vmcnt waited only inside the fallback.
//  (3) Winner's demand carried through the DPP reduces -> no post-pick
//      s_du gather on the critical chain.
// LDS: thr becomes uint2/row (16KB) so s_lr moves to global scratch
// (fire-and-forget stores; one vmcnt(0) drain before the deferred pass).
// Certification soundness: margin EGM covers the 21-bit packing error
// (rows with top-15 |g|>=128 flagged -> thr=+inf -> always exact path);
// B-tests use round-UP bf16 thresholds (conservative); exact ties always
// fail the EGM margin -> exact fallback. Tier-2 = exact 128-list eval +
// convex B2. Tier-3 = R5-verbatim full-row scan. Scores exact, deferred.

#define NN 2048
#define HH 1024
#define TSTEPS (NN + NN / 8)   // 2304 = 3*768
#define TILE 64
#define KT 16
#define KCAND 128
#define KL 15

// ---------------- pack Wq[:, :H] into ld=1024 buffer ----------------
__global__ __launch_bounds__(256) void prep_wqh(const float* __restrict__ Wq,
                                                float* __restrict__ Wqh) {
  int id = blockIdx.x * 256 + threadIdx.x;
  int r = id >> 10, c = id & 1023;
  Wqh[id] = Wq[r * (HH + 2) + c];
}

// ---------------- NT GEMM: C[M,N] = A[M,K] @ B[N,K]^T (+ bias[n]) ----------------
__global__ __launch_bounds__(256) void gemm_nt(const float* __restrict__ A, int lda,
                                               const float* __restrict__ B, int ldb,
                                               float* __restrict__ C, int ldc,
                                               int K, const float* __restrict__ bias) {
  __shared__ float As[KT][TILE + 4];
  __shared__ float Bs[KT][TILE + 4];
  const int i0 = blockIdx.y * TILE;
  const int j0 = blockIdx.x * TILE;
  const int t = threadIdx.x;
  const int srow = t >> 2, sq = t & 3;
  const int tx = t & 15, ty = t >> 4;
  float acc[4][4] = {};
  for (int k0 = 0; k0 < K; k0 += KT) {
    float4 av = *(const float4*)&A[(size_t)(i0 + srow) * lda + k0 + sq * 4];
    float4 bv = *(const float4*)&B[(size_t)(j0 + srow) * ldb + k0 + sq * 4];
    __syncthreads();
    As[sq * 4 + 0][srow] = av.x; As[sq * 4 + 1][srow] = av.y;
    As[sq * 4 + 2][srow] = av.z; As[sq * 4 + 3][srow] = av.w;
    Bs[sq * 4 + 0][srow] = bv.x; Bs[sq * 4 + 1][srow] = bv.y;
    Bs[sq * 4 + 2][srow] = bv.z; Bs[sq * 4 + 3][srow] = bv.w;
    __syncthreads();
#pragma unroll
    for (int k = 0; k < KT; ++k) {
      float4 a4 = *(const float4*)&As[k][ty * 4];
      float4 b4 = *(const float4*)&Bs[k][tx * 4];
      float a[4] = {a4.x, a4.y, a4.z, a4.w};
      float b[4] = {b4.x, b4.y, b4.z, b4.w};
#pragma unroll
      for (int m = 0; m < 4; ++m)
#pragma unroll
        for (int n = 0; n < 4; ++n) acc[m][n] = fmaf(a[m], b[n], acc[m][n]);
    }
  }
  float bb[4] = {0.f, 0.f, 0.f, 0.f};
  if (bias) {
#pragma unroll
    for (int n = 0; n < 4; ++n) bb[n] = bias[j0 + tx * 4 + n];
  }
#pragma unroll
  for (int m = 0; m < 4; ++m) {
    float4 st = {acc[m][0] + bb[0], acc[m][1] + bb[1], acc[m][2] + bb[2], acc[m][3] + bb[3]};
    *(float4*)&C[(size_t)(i0 + ty * 4 + m) * ldc + j0 + tx * 4] = st;
  }
}

// ---------------- u_i = K_i . Wq[:,H], v_i = K_i . bq  (one wave per row) ---------
__global__ __launch_bounds__(64) void uv_k(const float* __restrict__ Kmat,
                                           const float* __restrict__ Wq,
                                           const float* __restrict__ bq,
                                           float* __restrict__ u, float* __restrict__ v) {
  int i = blockIdx.x;
  int lane = threadIdx.x;
  float su = 0.f, sv = 0.f;
#pragma unroll
  for (int m = 0; m < HH / 64; ++m) {
    int j = lane + 64 * m;
    float kv = Kmat[(size_t)i * HH + j];
    su = fmaf(kv, Wq[(size_t)j * (HH + 2) + HH], su);
    sv = fmaf(kv, bq[j], sv);
  }
#pragma unroll
  for (int off = 32; off; off >>= 1) {
    su += __shfl_down(su, off, 64);
    sv += __shfl_down(sv, off, 64);
  }
  if (lane == 0) { u[i] = su; v[i] = sv; }
}

// ---------------- umax = max |u| (kept: harmless, used nowhere hot now) ----------
__global__ __launch_bounds__(256) void umax_k(const float* __restrict__ u,
                                              float* __restrict__ umaxp) {
  __shared__ float sm[256];
  int t = threadIdx.x;
  float m = 0.f;
  for (int i = t; i < NN; i += 256) m = fmaxf(m, fabsf(u[i]));
  sm[t] = m;
  __syncthreads();
  for (int s = 128; s; s >>= 1) {
    if (t < s) sm[t] = fmaxf(sm[t], sm[t + s]);
    __syncthreads();
  }
  if (t == 0) *umaxp = sm[0];
}

// ---------------- per-row exact top-K by g: 4-pass radix-select ----------------
__device__ __forceinline__ unsigned f2key(float f) {
  unsigned x = __float_as_uint(f);
  return x ^ ((x >> 31) ? 0xFFFFFFFFu : 0x80000000u);  // monotonic asc mapping
}
__device__ __forceinline__ float key2f(unsigned k) {
  unsigned x = (k & 0x80000000u) ? (k ^ 0x80000000u) : ~k;
  return __uint_as_float(x);
}
// bf16-style round-UP (toward +inf) of a float. ub16f(x) >= x always.
__device__ __forceinline__ unsigned ub16(float x) {
  unsigned b = __float_as_uint(x);
  if (x > 0.f && (b & 0xFFFFu)) b += 0x10000u;
  return b >> 16;
}
// Produces: cand[row][0..127] exact top-128 (value,idx); pc16[row][0..14]
// packed top-15 (key&~0x7FF | idx); thrpk2[row] = uint2:
//   .x = ub16(thr15)<<16 | ub16(M1_15)    (+inf halves when row flagged)
//   .y = ub16(thr128)<<16 | ub16(M1_128)
// where M1_K = max over j NOT in the stored top-K list of (g_j + u_j).
// Convex bound: for lr in [0,1], any outside node's t = g + lr*u satisfies
// t <= (1-lr)*thrK + lr*M1_K  (linearity in lr; both endpoint maxima bounded).
__global__ __launch_bounds__(256) void prep_cand(const float* __restrict__ GT,
                                                 const float* __restrict__ u,
                                                 uint2* __restrict__ cand,
                                                 unsigned* __restrict__ pc16,
                                                 uint2* __restrict__ thrpk2) {
  __shared__ float rowv[NN];
  __shared__ float su_[NN];
  __shared__ int hist[256];
  __shared__ float red15[256];
  __shared__ float red128[256];
  __shared__ unsigned c128k[KCAND];
  __shared__ int c128i[KCAND];
  __shared__ unsigned char markA[NN];  // in stored top-128
  __shared__ unsigned char markB[NN];  // in stored top-15
  __shared__ int s_d, s_need, s_gt, s_eq, s_gt2, s_eq2, s_flag;
  const int row = blockIdx.x, t = threadIdx.x;
  for (int i = t; i < NN; i += 256) {
    rowv[i] = GT[(size_t)row * NN + i];
    su_[i] = u[i];
    markA[i] = 0;
    markB[i] = 0;
  }
  __syncthreads();
  unsigned prefix = 0;
  int need = KCAND;
  for (int pass = 0; pass < 4; ++pass) {
    hist[t] = 0;
    __syncthreads();
    const int shift = 24 - 8 * pass;
    for (int i = t; i < NN; i += 256) {
      unsigned k = f2key(rowv[i]);
      if (pass == 0 || (k >> (shift + 8)) == (prefix >> (shift + 8)))
        atomicAdd(&hist[(k >> shift) & 0xFF], 1);
    }
    __syncthreads();
    if (t == 0) {
      int cum = 0, d = 255;
      for (; d > 0; --d) {
        if (cum + hist[d] >= need) break;
        cum += hist[d];
      }
      s_d = d;
      s_need = need - cum;
    }
    __syncthreads();
    prefix |= ((unsigned)s_d) << shift;
    need = s_need;
    __syncthreads();
  }
  const unsigned thrk = prefix;  // exact KCAND-th largest key
  if (t == 0) { s_gt = 0; s_eq = 0; }
  __syncthreads();
  for (int i = t; i < NN; i += 256) {
    unsigned k = f2key(rowv[i]);
    if (k > thrk) {
      int p = atomicAdd(&s_gt, 1);
      cand[(size_t)row * KCAND + p] = make_uint2(__float_as_uint(rowv[i]), (unsigned)i);
      c128k[p] = k;
      c128i[p] = i;
      markA[i] = 1;
    }
  }
  __syncthreads();
  const int cgt = s_gt;
  for (int i = t; i < NN; i += 256) {
    if (f2key(rowv[i]) == thrk) {
      int p = atomicAdd(&s_eq, 1);
      if (p < KCAND - cgt) {
        cand[(size_t)row * KCAND + cgt + p] = make_uint2(__float_as_uint(rowv[i]), (unsigned)i);
        c128k[cgt + p] = thrk;
        c128i[cgt + p] = i;
        markA[i] = 1;
      }
    }
  }
  __syncthreads();
  // ---- exact 15th-largest among the 128 keys (== row's top-15 multiset)
  unsigned pfx2 = 0;
  need = KL;
  for (int pass = 0; pass < 4; ++pass) {
    hist[t] = 0;
    __syncthreads();
    const int shift = 24 - 8 * pass;
    for (int i = t; i < KCAND; i += 256) {
      unsigned k = c128k[i];
      if (pass == 0 || (k >> (shift + 8)) == (pfx2 >> (shift + 8)))
        atomicAdd(&hist[(k >> shift) & 0xFF], 1);
    }
    __syncthreads();
    if (t == 0) {
      int cum = 0, d = 255;
      for (; d > 0; --d) {
        if (cum + hist[d] >= need) break;
        cum += hist[d];
      }
      s_d = d;
      s_need = need - cum;
    }
    __syncthreads();
    pfx2 |= ((unsigned)s_d) << shift;
    need = s_need;
    __syncthreads();
  }
  const unsigned thrk15 = pfx2;
  if (t == 0) { s_gt2 = 0; s_eq2 = 0; s_flag = 0; }
  __syncthreads();
  for (int i = t; i < KCAND; i += 256) {
    if (c128k[i] > thrk15) {
      int p = atomicAdd(&s_gt2, 1);
      pc16[(size_t)row * KL + p] = (c128k[i] & 0xFFFFF800u) | (unsigned)c128i[i];
      markB[c128i[i]] = 1;
      if (fabsf(key2f(c128k[i])) >= 128.0f) s_flag = 1;
    }
  }
  __syncthreads();
  const int cgt2 = s_gt2;
  for (int i = t; i < KCAND; i += 256) {
    if (c128k[i] == thrk15) {
      int p = atomicAdd(&s_eq2, 1);
      if (p < KL - cgt2) {
        pc16[(size_t)row * KL + cgt2 + p] = (thrk15 & 0xFFFFF800u) | (unsigned)c128i[i];
        markB[c128i[i]] = 1;
      }
    }
  }
  if (t == 0 && fabsf(key2f(thrk15)) >= 128.0f) s_flag = 1;
  __syncthreads();
  // ---- M1_15 / M1_128: max of (g + u) over nodes outside each stored list
  float lm15 = -__builtin_inff(), lm128 = -__builtin_inff();
  for (int i = t; i < NN; i += 256) {
    float gu = rowv[i] + su_[i];
    if (!markB[i]) lm15 = fmaxf(lm15, gu);
    if (!markA[i]) lm128 = fmaxf(lm128, gu);
  }
  red15[t] = lm15;
  red128[t] = lm128;
  __syncthreads();
  for (int s = 128; s; s >>= 1) {
    if (t < s) {
      red15[t] = fmaxf(red15[t], red15[t + s]);
      red128[t] = fmaxf(red128[t], red128[t + s]);
    }
    __syncthreads();
  }
  if (t == 0) {
    const float INF = __builtin_inff();
    float t15 = s_flag ? INF : key2f(thrk15);
    float m15 = s_flag ? INF : red15[0];
    thrpk2[row] = make_uint2((ub16(t15) << 16) | ub16(m15),
                             (ub16(key2f(thrk)) << 16) | ub16(red128[0]));
  }
}

// ---------------- LLC pre-warm for the tier-2 fallback lists ---------------------
__global__ __launch_bounds__(256) void warm_k(const float* __restrict__ a, int n,
                                              float* __restrict__ sink) {
  float s = 0.f;
  const float4* a4 = (const float4*)a;
  for (int i = threadIdx.x; i < n / 4; i += 256) {
    float4 x = a4[i];
    s += x.x + x.y + x.z + x.w;
  }
  if (s == 1.2345e-30f) sink[blockIdx.x] = s;  // never true; keeps loads alive
}

// DPP merge of (bv,bi,bd): max value, smallest index on ties; bd = winner's
// demand payload. Invalid lanes carry (-inf, INT_MAX, 0).
#define DPP_MERGE3(CTRL)                                                      \
  {                                                                           \
    int ovb = __builtin_amdgcn_update_dpp(                                    \
        (int)0xFF800000, __float_as_int(bv), (CTRL), 0xf, 0xf, false);        \
    int oib = __builtin_amdgcn_update_dpp(                                    \
        0x7fffffff, bi, (CTRL), 0xf, 0xf, false);                             \
    int odb = __builtin_amdgcn_update_dpp(                                    \
        0, __float_as_int(bd), (CTRL), 0xf, 0xf, false);                      \
    float ov = __int_as_float(ovb);                                           \
    if (ov > bv || (ov == bv && oib < bi)) {                                  \
      bv = ov; bi = oib; bd = __int_as_float(odb);                            \
    }                                                                         \
  }

// DPP top-2 merge with demand payload: (bv1,bi1,bd1) = max w/ min-idx ties;
// bv2 = runner-up VALUE of the union (top2 of {a1,a2}∪{b1,b2} =
// {max, max(min(a1,b1), a2, b2)}).
#define DPP_TOP2D(CTRL)                                                       \
  {                                                                           \
    int ovb = __builtin_amdgcn_update_dpp(                                    \
        (int)0xFF800000, __float_as_int(bv1), (CTRL), 0xf, 0xf, false);       \
    int oib = __builtin_amdgcn_update_dpp(                                    \
        0x7fffffff, bi1, (CTRL), 0xf, 0xf, false);                            \
    int odb = __builtin_amdgcn_update_dpp(                                    \
        0, __float_as_int(bd1), (CTRL), 0xf, 0xf, false);                     \
    int ov2b = __builtin_amdgcn_update_dpp(                                   \
        (int)0xFF800000, __float_as_int(bv2), (CTRL), 0xf, 0xf, false);       \
    float ov1 = __int_as_float(ovb);                                          \
    float ov2 = __int_as_float(ov2b);                                         \
    float lose = fminf(bv1, ov1);                                             \
    if (ov1 > bv1 || (ov1 == bv1 && oib < bi1)) {                             \
      bv1 = ov1; bi1 = oib; bd1 = __int_as_float(odb);                        \
    }                                                                         \
    bv2 = fmaxf(fmaxf(bv2, ov2), lose);                                       \
  }

// ---------------- sequential decode: ONE wave ------------------------------------
// Certified path: pure LDS+VALU. Spec tier-2 load is VMEM-only (vmcnt),
// waited only inside the fallback branch.
__global__ __launch_bounds__(64, 1) void decode(const float* __restrict__ GT,
                                                const uint2* __restrict__ cand,
                                                const unsigned* __restrict__ pc16,
                                                const uint2* __restrict__ thrpk2,
                                                const float* __restrict__ u,
                                                const float* __restrict__ demands,
                                                const int* __restrict__ capp,
                                                const int* __restrict__ depotp,
                                                float* __restrict__ lrbuf,
                                                float* __restrict__ out) {
  __shared__ __align__(16) unsigned s_pc[NN * KL + 64];   // 123.1 KB packed lists
  __shared__ __align__(16) float2 s_du[NN];               // 16 KB (.x=d|+inf, .y=u)
  __shared__ __align__(16) uint2 s_thr[NN];               // 16 KB packed thresholds
  __shared__ __align__(16) unsigned short s_tour[TSTEPS + 2];  // 4.6 KB

  const int lane = threadIdx.x;
  const int depot = *depotp;
  const float capf = (float)(*capp);
  const float INF = __builtin_inff();
  const float NEGINF = -INF;
  const float C0 = 0.015625f;   // ALPHA / sqrt(HID), exact power of two
  const float MARGIN = 0.5f;    // >> any fp32 rounding in the bounds
  const float EGM = 0.0625f;    // > 2x packing error (0.0156 @ |g|<128) + rounding
  float* sduf = (float*)s_du;

  for (int i = lane; i < NN; i += 64) {
    s_du[i] = make_float2(demands[i], u[i]);
    s_thr[i] = thrpk2[i];
  }
  {
    const uint4* p4 = (const uint4*)pc16;
    uint4* q4 = (uint4*)s_pc;
    for (int i = lane; i < NN * KL / 4; i += 64) q4[i] = p4[i];
  }
  if (lane == 0) {
    sduf[2 * depot] = INF;  // depot starts visited
    s_tour[0] = (unsigned short)depot;
  }
  // single wave: per-wave LDS ordering suffices; no barrier needed

  int done = 0, ntaken = 0, lasts = depot;
  float load = capf;
  float lr = load / capf;  // same fp32 division as reference
  int step = 0;
  const int lcl = (lane < KL) ? lane : (KL - 1);  // lanes >=15 broadcast entry 14
  uint4 cc0, cc1, cc2;  // 3-deep rotated speculative tier-2 row registers

#define STEP_ONE(CC)                                                            \
  {                                                                             \
    if (done) goto FLUSH;                                                       \
    const int row = lasts;                                                      \
    /* speculative tier-2 row load: VMEM only (vmcnt); consumed only on miss */ \
    CC = ((const uint4*)(cand + (size_t)row * KCAND))[lane];                    \
    /* ---- tier-1: 15 packed candidates, lanes 0-14 (pure LDS + VALU) */       \
    unsigned pw = s_pc[row * KL + lcl];                                         \
    uint2 pk2 = s_thr[row];                                                     \
    int i1x = (int)(pw & 0x7FFu);                                               \
    float g1 = key2f(pw & 0xFFFFF800u);  /* ghat <= g <= ghat + 0.0156 */       \
    float2 du1 = s_du[i1x];              /* one ds_read_b64 */                  \
    float t1 = fmaf(du1.y, lr, g1);                                             \
    bool act = (lane < KL) && (du1.x <= load);                                  \
    float bv1 = act ? t1 : NEGINF;                                              \
    int bi1 = act ? i1x : 0x7fffffff;                                           \
    float bd1 = act ? du1.x : 0.f;                                              \
    float bv2 = NEGINF;                                                         \
    DPP_TOP2D(0x111); DPP_TOP2D(0x112); DPP_TOP2D(0x114); DPP_TOP2D(0x118);     \
    float rv1 = __int_as_float(__builtin_amdgcn_readlane(__float_as_int(bv1), 15)); \
    int ri1 = __builtin_amdgcn_readlane(bi1, 15);                               \
    float rv2 = __int_as_float(__builtin_amdgcn_readlane(__float_as_int(bv2), 15)); \
    float rd1 = __int_as_float(__builtin_amdgcn_readlane(__float_as_int(bd1), 15)); \
    /* convex bound over outside-of-15 nodes: (1-lr)*thr15 + lr*M1_15 */        \
    float t15 = __uint_as_float(pk2.x & 0xFFFF0000u);                           \
    float m15 = __uint_as_float(pk2.x << 16);                                   \
    float B1 = fmaf(1.0f - lr, t15, lr * m15) + MARGIN;                         \
    int take, nxt;                                                              \
    float dwin;                                                                 \
    if (rv1 > B1 && rv1 > rv2 + EGM) {                                          \
      /* certified: true t_w >= rv1 (ghat<=g), rv1 > rv2+EGM beats every other  \
         in-list true t (packing err < EGM/2 each side), rv1 > B1 beats every   \
         outside node for this lr. Unique argmax == ref's pick. */              \
      take = 1; nxt = ri1; dwin = rd1;                                          \
    } else {                                                                    \
      /* ---- tier-2: exact eval of the 128-list (spec load already in flight) */ \
      float bv = NEGINF;                                                        \
      int bi = 0x7fffffff;                                                      \
      float bd = 0.f;                                                           \
      {                                                                         \
        float ga = __uint_as_float(CC.x); int ia = (int)CC.y;                   \
        float gb = __uint_as_float(CC.z); int ib = (int)CC.w;                   \
        float2 da = s_du[ia];                                                   \
        float2 db = s_du[ib];                                                   \
        float ta = fmaf(da.y, lr, ga);                                          \
        float tb = fmaf(db.y, lr, gb);                                          \
        if ((da.x <= load) && (ta > bv || (ta == bv && ia < bi))) {             \
          bv = ta; bi = ia; bd = da.x;                                          \
        }                                                                       \
        if ((db.x <= load) && (tb > bv || (tb == bv && ib < bi))) {             \
          bv = tb; bi = ib; bd = db.x;                                          \
        }                                                                       \
      }                                                                         \
      DPP_MERGE3(0x111); DPP_MERGE3(0x112); DPP_MERGE3(0x114);                  \
      DPP_MERGE3(0x118); DPP_MERGE3(0x142); DPP_MERGE3(0x143);                  \
      float rbv = __int_as_float(__builtin_amdgcn_readlane(__float_as_int(bv), 63)); \
      int rbi = __builtin_amdgcn_readlane(bi, 63);                              \
      float rbd = __int_as_float(__builtin_amdgcn_readlane(__float_as_int(bd), 63)); \
      float t128 = __uint_as_float(pk2.y & 0xFFFF0000u);                        \
      float m128 = __uint_as_float(pk2.y << 16);                                \
      float B2 = fmaf(1.0f - lr, t128, lr * m128) + MARGIN;                     \
      if (rbv > B2) {                                                           \
        take = 1; nxt = rbi; dwin = rbd;                                        \
      } else {                                                                  \
        /* ---- tier-3: R5-verbatim exact full-row scan */                      \
        const float4* rowp = (const float4*)(GT + (size_t)row * NN);            \
        const float4* du4 = (const float4*)s_du;                                \
        float fv = NEGINF;                                                      \
        int fi = NN;                                                            \
        float fd = 0.f;                                                         \
        _Pragma("unroll") for (int r = 0; r < 8; ++r) {                         \
          float4 g4 = rowp[r * 64 + lane];                                      \
          float4 pA = du4[(r * 64 + lane) * 2];      /* d0,u0,d1,u1 */          \
          float4 pB = du4[(r * 64 + lane) * 2 + 1];  /* d2,u2,d3,u3 */          \
          float gl[4] = {g4.x, g4.y, g4.z, g4.w};                               \
          float dl[4] = {pA.x, pA.z, pB.x, pB.z};                               \
          float ul[4] = {pA.y, pA.w, pB.y, pB.w};                               \
          float cv = NEGINF;                                                    \
          int cj = 0;                                                           \
          _Pragma("unroll") for (int j = 0; j < 4; ++j) {                       \
            float tt = fmaf(ul[j], lr, gl[j]);                                  \
            bool feas = (dl[j] <= load);                                        \
            if (feas && tt > cv) { cv = tt; cj = j; }                           \
          }                                                                     \
          if (cv > fv) { fv = cv; fi = 4 * (r * 64 + lane) + cj; fd = dl[cj]; } \
        }                                                                       \
        float bv = fv;                                                          \
        int bi = fi;                                                            \
        float bd = fd;                                                          \
        DPP_MERGE3(0x111); DPP_MERGE3(0x112); DPP_MERGE3(0x114);                \
        DPP_MERGE3(0x118); DPP_MERGE3(0x142); DPP_MERGE3(0x143);                \
        float fbv = __int_as_float(__builtin_amdgcn_readlane(__float_as_int(bv), 63)); \
        int fbi = __builtin_amdgcn_readlane(bi, 63);                            \
        float fbd = __int_as_float(__builtin_amdgcn_readlane(__float_as_int(bd), 63)); \
        take = (fbv > NEGINF) ? 1 : 0;                                          \
        nxt = take ? fbi : depot;                                               \
        dwin = fbd;                                                             \
      }                                                                         \
    }                                                                           \
    /* ---- state update + output stores (identical fp ops to ref) */           \
    if (lane == 0) {                                                            \
      s_tour[1 + step] = (unsigned short)nxt;                                   \
      lrbuf[step] = take ? lr : -1.0f;  /* fire-and-forget global store */      \
    }                                                                           \
    if (take) {                                                                 \
      load = load - dwin;  /* dwin == raw demands[nxt], same fp op as ref */    \
      ntaken++;                                                                 \
      if (lane == 0) sduf[2 * nxt] = INF;                                       \
    } else {                                                                    \
      load = capf;                                                              \
      if (ntaken == NN - 1) done = 1;                                           \
    }                                                                           \
    lasts = nxt;                                                                \
    lr = load / capf;  /* same fp32 division as reference */                    \
    ++step;                                                                     \
  }

  for (int s3 = 0; s3 < TSTEPS; s3 += 3) {  // 2304 = 3*768
    STEP_ONE(cc0)
    STEP_ONE(cc1)
    STEP_ONE(cc2)
  }
FLUSH:
  // ref emits (depot, 0) forever once done
  for (int q = step + lane; q < TSTEPS; q += 64) {
    s_tour[1 + q] = (unsigned short)depot;
    lrbuf[q] = -1.0f;
  }
  // drain all outstanding global stores (lrbuf) before reading them back
  asm volatile("s_waitcnt vmcnt(0)" ::: "memory");
  // ---- flush tour; compute scores exactly in a parallel deferred pass
  for (int i = lane; i <= TSTEPS; i += 64) out[i] = (float)s_tour[i];
  for (int s = lane; s < TSTEPS; s += 64) {
    float lrs = lrbuf[s];
    float sc = 0.0f;
    if (lrs >= 0.0f) {
      int lastI = (int)s_tour[s];
      int biI = (int)s_tour[s + 1];
      float g = GT[(size_t)lastI * NN + biI];
      sc = fmaf(s_du[biI].y, lrs, g) * C0;  // identical expression to R3-R11
    }
    out[1 + TSTEPS + s] = sc;
  }
#undef STEP_ONE
}

extern "C" void kernel_launch(void* const* d_in, const int* in_sizes, int n_in,
                              void* d_out, int out_size, void* d_ws, size_t ws_size,
                              hipStream_t stream) {
  const float* emb     = (const float*)d_in[0];  // [N, H]
  const float* demands = (const float*)d_in[1];  // [N]
  const float* Wq      = (const float*)d_in[2];  // [H, H+2]
  const float* bq      = (const float*)d_in[3];  // [H]
  const float* Wk      = (const float*)d_in[4];  // [H, H]
  const float* bk      = (const float*)d_in[5];  // [H]
  const int* cap       = (const int*)d_in[6];
  const int* depot     = (const int*)d_in[7];
  float* out           = (float*)d_out;          // 2305 tour + 2304 scores, fp32

  char* ws = (char*)d_ws;
  float* Kmat = (float*)(ws);                         // 8 MB  [N,H]
  float* Z    = (float*)(ws + ((size_t)8 << 20));     // 8 MB  [N,H]
  float* GT   = (float*)(ws + ((size_t)16 << 20));    // 16 MB [N,N] row=last, +v
  float* Wqh  = (float*)(ws + ((size_t)32 << 20));    // 4 MB  [H,H]; later overlaid
  float* u    = (float*)(ws + ((size_t)36 << 20));    // 8 KB
  float* v    = (float*)(ws + ((size_t)36 << 20) + 8192);
  float* umax = (float*)(ws + ((size_t)36 << 20) + 24576);
  float* sink = (float*)(ws + ((size_t)36 << 20) + 32768);  // warm sink (unused)
  // overlays of the dead Wqh region (Wqh dead after the Z GEMM):
  uint2* cnd  = (uint2*)Wqh;                                        // 2 MB
  unsigned* pc16g = (unsigned*)(ws + ((size_t)34 << 20));           // 120 KB
  uint2* thrpk2g  = (uint2*)(ws + ((size_t)34 << 20) + (128 << 10)); // 16 KB
  float* lrbuf    = (float*)(ws + ((size_t)34 << 20) + (160 << 10)); // 9.2 KB

  hipLaunchKernelGGL(prep_wqh, dim3(4096), dim3(256), 0, stream, Wq, Wqh);
  // K = emb @ Wk^T + bk
  hipLaunchKernelGGL(gemm_nt, dim3(HH / TILE, NN / TILE), dim3(256), 0, stream,
                     emb, HH, Wk, HH, Kmat, HH, HH, bk);
  // Z = emb @ Wqh^T
  hipLaunchKernelGGL(gemm_nt, dim3(HH / TILE, NN / TILE), dim3(256), 0, stream,
                     emb, HH, Wqh, HH, Z, HH, HH, (const float*)nullptr);
  // u_i = K_i . Wq[:,H], v_i = K_i . bq
  hipLaunchKernelGGL(uv_k, dim3(NN), dim3(64), 0, stream, Kmat, Wq, bq, u, v);
  hipLaunchKernelGGL(umax_k, dim3(1), dim3(256), 0, stream, u, umax);
  // GT = Z @ K^T + v (v==0 since bq==0 -> bit-identical)
  hipLaunchKernelGGL(gemm_nt, dim3(NN / TILE, NN / TILE), dim3(256), 0, stream,
                     Z, HH, Kmat, HH, GT, NN, HH, v);
  // top-128 lists + packed top-15 + convex-bound thresholds (overlay dead Wqh)
  hipLaunchKernelGGL(prep_cand, dim3(NN), dim3(256), 0, stream, GT, u, cnd,
                     pc16g, thrpk2g);
  // pre-warm LLC with cand (2 MB) + pc16/thr (136 KB) for decode
  hipLaunchKernelGGL(warm_k, dim3(128), dim3(256), 0, stream,
                     (const float*)cnd, NN * KCAND * 2 + (160 << 8), sink);
  hipLaunchKernelGGL(decode, dim3(1), dim3(64), 0, stream, GT, cnd,
                     pc16g, thrpk2g, u, demands, cap, depot, lrbuf, out);
}

// Round 4
// 1837.052 us; speedup vs baseline: 1.1395x; 1.1395x over previous
//
#include <hip/hip_runtime.h>
#include <hip/hip_bf16.h>

// BeamDecoder: greedy CVRP-style decode.
// s_i(step) = c*( G[last,i] + (load/cap)*u_i )   (v==0 since bq==0; folded)
//
// R13: R12's spec VMEM load regressed (decode 1482us, FETCH 672->1494KB):
// fallback rate was already ~8% (R11 FETCH arithmetic), so the certified
// path ITSELF costs ~1400cyc -- 3x the LDS+VALU model. Unmodeled cost on a
// single wave: giant 3x-unrolled body (tier-2 + ~250-inst tier-3 inlined
// thrice) -> taken branches over multi-KB cold code + icache pressure, plus
// a 9-op/stage 4-register DPP reduce. Fixes:
//  (1) drop spec load (R11 on-demand tier-2; FETCH back to ~670KB)
//  (2) tiny loop body: no unroll, tier-3 in a __noinline__ function,
//      __builtin_expect on the cert branch (hot path = compact fallthrough)
//  (3) packed single-u32 DPP reduce: key=(f2key(t)&~0x7FF)|(2047-idx);
//      max+runner-up = 6 ops/stage, no payload. Winner demand re-gathered
//      post-pick (uniform LDS read, overlaps next step's list read).
//      Soundness: rv1 decoded round-down (lower bd), rv2 round-up; trunc
//      collisions fail the EGM margin -> exact fallback. Prep flags rows
//      with any top-15 |g|+|u| >= 128 so in-list |t|<128 -> key-trunc err
//      <= 0.0156; EGM=0.0625 covers trunc+pack+rounding.
//  (4) keep R12 convex bounds B = (1-lr)*thrK + lr*M1_K + 0.5 (round-up
//      bf16 halves), uint2 thresholds in LDS.
// Tier-2 = exact 128-list eval (on-demand) + convex B2. Tier-3 = R5-verbatim
// full-row scan (noinline). Scores exact via deferred pass.

#define NN 2048
#define HH 1024
#define TSTEPS (NN + NN / 8)   // 2304
#define TILE 64
#define KT 16
#define KCAND 128
#define KL 15

// ---------------- pack Wq[:, :H] into ld=1024 buffer ----------------
__global__ __launch_bounds__(256) void prep_wqh(const float* __restrict__ Wq,
                                                float* __restrict__ Wqh) {
  int id = blockIdx.x * 256 + threadIdx.x;
  int r = id >> 10, c = id & 1023;
  Wqh[id] = Wq[r * (HH + 2) + c];
}

// ---------------- NT GEMM: C[M,N] = A[M,K] @ B[N,K]^T (+ bias[n]) ----------------
__global__ __launch_bounds__(256) void gemm_nt(const float* __restrict__ A, int lda,
                                               const float* __restrict__ B, int ldb,
                                               float* __restrict__ C, int ldc,
                                               int K, const float* __restrict__ bias) {
  __shared__ float As[KT][TILE + 4];
  __shared__ float Bs[KT][TILE + 4];
  const int i0 = blockIdx.y * TILE;
  const int j0 = blockIdx.x * TILE;
  const int t = threadIdx.x;
  const int srow = t >> 2, sq = t & 3;
  const int tx = t & 15, ty = t >> 4;
  float acc[4][4] = {};
  for (int k0 = 0; k0 < K; k0 += KT) {
    float4 av = *(const float4*)&A[(size_t)(i0 + srow) * lda + k0 + sq * 4];
    float4 bv = *(const float4*)&B[(size_t)(j0 + srow) * ldb + k0 + sq * 4];
    __syncthreads();
    As[sq * 4 + 0][srow] = av.x; As[sq * 4 + 1][srow] = av.y;
    As[sq * 4 + 2][srow] = av.z; As[sq * 4 + 3][srow] = av.w;
    Bs[sq * 4 + 0][srow] = bv.x; Bs[sq * 4 + 1][srow] = bv.y;
    Bs[sq * 4 + 2][srow] = bv.z; Bs[sq * 4 + 3][srow] = bv.w;
    __syncthreads();
#pragma unroll
    for (int k = 0; k < KT; ++k) {
      float4 a4 = *(const float4*)&As[k][ty * 4];
      float4 b4 = *(const float4*)&Bs[k][tx * 4];
      float a[4] = {a4.x, a4.y, a4.z, a4.w};
      float b[4] = {b4.x, b4.y, b4.z, b4.w};
#pragma unroll
      for (int m = 0; m < 4; ++m)
#pragma unroll
        for (int n = 0; n < 4; ++n) acc[m][n] = fmaf(a[m], b[n], acc[m][n]);
    }
  }
  float bb[4] = {0.f, 0.f, 0.f, 0.f};
  if (bias) {
#pragma unroll
    for (int n = 0; n < 4; ++n) bb[n] = bias[j0 + tx * 4 + n];
  }
#pragma unroll
  for (int m = 0; m < 4; ++m) {
    float4 st = {acc[m][0] + bb[0], acc[m][1] + bb[1], acc[m][2] + bb[2], acc[m][3] + bb[3]};
    *(float4*)&C[(size_t)(i0 + ty * 4 + m) * ldc + j0 + tx * 4] = st;
  }
}

// ---------------- u_i = K_i . Wq[:,H], v_i = K_i . bq  (one wave per row) ---------
__global__ __launch_bounds__(64) void uv_k(const float* __restrict__ Kmat,
                                           const float* __restrict__ Wq,
                                           const float* __restrict__ bq,
                                           float* __restrict__ u, float* __restrict__ v) {
  int i = blockIdx.x;
  int lane = threadIdx.x;
  float su = 0.f, sv = 0.f;
#pragma unroll
  for (int m = 0; m < HH / 64; ++m) {
    int j = lane + 64 * m;
    float kv = Kmat[(size_t)i * HH + j];
    su = fmaf(kv, Wq[(size_t)j * (HH + 2) + HH], su);
    sv = fmaf(kv, bq[j], sv);
  }
#pragma unroll
  for (int off = 32; off; off >>= 1) {
    su += __shfl_down(su, off, 64);
    sv += __shfl_down(sv, off, 64);
  }
  if (lane == 0) { u[i] = su; v[i] = sv; }
}

// ---------------- per-row exact top-K by g: 4-pass radix-select ----------------
__device__ __forceinline__ unsigned f2key(float f) {
  unsigned x = __float_as_uint(f);
  return x ^ ((x >> 31) ? 0xFFFFFFFFu : 0x80000000u);  // monotonic asc mapping
}
__device__ __forceinline__ float key2f(unsigned k) {
  unsigned x = (k & 0x80000000u) ? (k ^ 0x80000000u) : ~k;
  return __uint_as_float(x);
}
// bf16-style round-UP (toward +inf) of a float. ub16f(x) >= x always.
__device__ __forceinline__ unsigned ub16(float x) {
  unsigned b = __float_as_uint(x);
  if (x > 0.f && (b & 0xFFFFu)) b += 0x10000u;
  return b >> 16;
}
// Produces: cand[row][0..127] exact top-128 (value,idx); pc16[row][0..14]
// packed top-15 (key&~0x7FF | idx); thrpk2[row] = uint2:
//   .x = ub16(thr15)<<16 | ub16(M1_15)    (+inf halves when row flagged)
//   .y = ub16(thr128)<<16 | ub16(M1_128)
// where M1_K = max over j NOT in the stored top-K list of (g_j + u_j).
// Flag: any stored top-15 entry with |g|+|u| >= 128 (bounds both the 21-bit
// g-pack error and the decode-side t-key truncation error to <= 0.0156).
__global__ __launch_bounds__(256) void prep_cand(const float* __restrict__ GT,
                                                 const float* __restrict__ u,
                                                 uint2* __restrict__ cand,
                                                 unsigned* __restrict__ pc16,
                                                 uint2* __restrict__ thrpk2) {
  __shared__ float rowv[NN];
  __shared__ float su_[NN];
  __shared__ int hist[256];
  __shared__ float red15[256];
  __shared__ float red128[256];
  __shared__ unsigned c128k[KCAND];
  __shared__ int c128i[KCAND];
  __shared__ unsigned char markA[NN];  // in stored top-128
  __shared__ unsigned char markB[NN];  // in stored top-15
  __shared__ int s_d, s_need, s_gt, s_eq, s_gt2, s_eq2, s_flag;
  const int row = blockIdx.x, t = threadIdx.x;
  for (int i = t; i < NN; i += 256) {
    rowv[i] = GT[(size_t)row * NN + i];
    su_[i] = u[i];
    markA[i] = 0;
    markB[i] = 0;
  }
  __syncthreads();
  unsigned prefix = 0;
  int need = KCAND;
  for (int pass = 0; pass < 4; ++pass) {
    hist[t] = 0;
    __syncthreads();
    const int shift = 24 - 8 * pass;
    for (int i = t; i < NN; i += 256) {
      unsigned k = f2key(rowv[i]);
      if (pass == 0 || (k >> (shift + 8)) == (prefix >> (shift + 8)))
        atomicAdd(&hist[(k >> shift) & 0xFF], 1);
    }
    __syncthreads();
    if (t == 0) {
      int cum = 0, d = 255;
      for (; d > 0; --d) {
        if (cum + hist[d] >= need) break;
        cum += hist[d];
      }
      s_d = d;
      s_need = need - cum;
    }
    __syncthreads();
    prefix |= ((unsigned)s_d) << shift;
    need = s_need;
    __syncthreads();
  }
  const unsigned thrk = prefix;  // exact KCAND-th largest key
  if (t == 0) { s_gt = 0; s_eq = 0; }
  __syncthreads();
  for (int i = t; i < NN; i += 256) {
    unsigned k = f2key(rowv[i]);
    if (k > thrk) {
      int p = atomicAdd(&s_gt, 1);
      cand[(size_t)row * KCAND + p] = make_uint2(__float_as_uint(rowv[i]), (unsigned)i);
      c128k[p] = k;
      c128i[p] = i;
      markA[i] = 1;
    }
  }
  __syncthreads();
  const int cgt = s_gt;
  for (int i = t; i < NN; i += 256) {
    if (f2key(rowv[i]) == thrk) {
      int p = atomicAdd(&s_eq, 1);
      if (p < KCAND - cgt) {
        cand[(size_t)row * KCAND + cgt + p] = make_uint2(__float_as_uint(rowv[i]), (unsigned)i);
        c128k[cgt + p] = thrk;
        c128i[cgt + p] = i;
        markA[i] = 1;
      }
    }
  }
  __syncthreads();
  // ---- exact 15th-largest among the 128 keys (== row's top-15 multiset)
  unsigned pfx2 = 0;
  need = KL;
  for (int pass = 0; pass < 4; ++pass) {
    hist[t] = 0;
    __syncthreads();
    const int shift = 24 - 8 * pass;
    for (int i = t; i < KCAND; i += 256) {
      unsigned k = c128k[i];
      if (pass == 0 || (k >> (shift + 8)) == (pfx2 >> (shift + 8)))
        atomicAdd(&hist[(k >> shift) & 0xFF], 1);
    }
    __syncthreads();
    if (t == 0) {
      int cum = 0, d = 255;
      for (; d > 0; --d) {
        if (cum + hist[d] >= need) break;
        cum += hist[d];
      }
      s_d = d;
      s_need = need - cum;
    }
    __syncthreads();
    pfx2 |= ((unsigned)s_d) << shift;
    need = s_need;
    __syncthreads();
  }
  const unsigned thrk15 = pfx2;
  if (t == 0) { s_gt2 = 0; s_eq2 = 0; s_flag = 0; }
  __syncthreads();
  for (int i = t; i < KCAND; i += 256) {
    if (c128k[i] > thrk15) {
      int p = atomicAdd(&s_gt2, 1);
      pc16[(size_t)row * KL + p] = (c128k[i] & 0xFFFFF800u) | (unsigned)c128i[i];
      markB[c128i[i]] = 1;
      if (fabsf(key2f(c128k[i])) + fabsf(su_[c128i[i]]) >= 128.0f) s_flag = 1;
    }
  }
  __syncthreads();
  const int cgt2 = s_gt2;
  for (int i = t; i < KCAND; i += 256) {
    if (c128k[i] == thrk15) {
      int p = atomicAdd(&s_eq2, 1);
      if (p < KL - cgt2) {
        pc16[(size_t)row * KL + cgt2 + p] = (thrk15 & 0xFFFFF800u) | (unsigned)c128i[i];
        markB[c128i[i]] = 1;
        if (fabsf(key2f(thrk15)) + fabsf(su_[c128i[i]]) >= 128.0f) s_flag = 1;
      }
    }
  }
  if (t == 0 && fabsf(key2f(thrk15)) >= 128.0f) s_flag = 1;
  __syncthreads();
  // ---- M1_15 / M1_128: max of (g + u) over nodes outside each stored list
  float lm15 = -__builtin_inff(), lm128 = -__builtin_inff();
  for (int i = t; i < NN; i += 256) {
    float gu = rowv[i] + su_[i];
    if (!markB[i]) lm15 = fmaxf(lm15, gu);
    if (!markA[i]) lm128 = fmaxf(lm128, gu);
  }
  red15[t] = lm15;
  red128[t] = lm128;
  __syncthreads();
  for (int s = 128; s; s >>= 1) {
    if (t < s) {
      red15[t] = fmaxf(red15[t], red15[t + s]);
      red128[t] = fmaxf(red128[t], red128[t + s]);
    }
    __syncthreads();
  }
  if (t == 0) {
    const float INF = __builtin_inff();
    float t15 = s_flag ? INF : key2f(thrk15);
    float m15 = s_flag ? INF : red15[0];
    thrpk2[row] = make_uint2((ub16(t15) << 16) | ub16(m15),
                             (ub16(key2f(thrk)) << 16) | ub16(red128[0]));
  }
}

// ---------------- LLC pre-warm for the tier-2 fallback lists ---------------------
__global__ __launch_bounds__(256) void warm_k(const float* __restrict__ a, int n,
                                              float* __restrict__ sink) {
  float s = 0.f;
  const float4* a4 = (const float4*)a;
  for (int i = threadIdx.x; i < n / 4; i += 256) {
    float4 x = a4[i];
    s += x.x + x.y + x.z + x.w;
  }
  if (s == 1.2345e-30f) sink[blockIdx.x] = s;  // never true; keeps loads alive
}

// DPP merge of (bv,bi): max value, smallest index on ties. Invalid lanes get
// (-inf, INT_MAX).
#define DPP_MERGE2(CTRL)                                                      \
  {                                                                           \
    int ovb = __builtin_amdgcn_update_dpp(                                    \
        (int)0xFF800000, __float_as_int(bv), (CTRL), 0xf, 0xf, false);        \
    int oib = __builtin_amdgcn_update_dpp(                                    \
        0x7fffffff, bi, (CTRL), 0xf, 0xf, false);                             \
    float ov = __int_as_float(ovb);                                           \
    if (ov > bv || (ov == bv && oib < bi)) { bv = ov; bi = oib; }             \
  }

// Packed u32 max + runner-up over a 16-lane DPP row. m1 = max key,
// m2 = runner-up key of the union. key 0 = invalid sentinel (< all valid
// keys since f2key(-inf)=0x007FFFFF > 0).
#define KRED(CTRL)                                                            \
  {                                                                           \
    unsigned o1 = (unsigned)__builtin_amdgcn_update_dpp(                      \
        0, (int)m1, (CTRL), 0xf, 0xf, false);                                 \
    unsigned o2 = (unsigned)__builtin_amdgcn_update_dpp(                      \
        0, (int)m2, (CTRL), 0xf, 0xf, false);                                 \
    unsigned mn = min(m1, o1);                                                \
    m1 = max(m1, o1);                                                         \
    m2 = max(max(m2, o2), mn);                                                \
  }

struct Pick { int take; int nxt; };

// Tier-3: R5-verbatim exact full-row scan. Cold; kept out of the hot loop's
// instruction stream.
__device__ __noinline__ Pick tier3_scan(const float* __restrict__ GT,
                                        const float2* sdu, int row, int lane,
                                        float load, float lr, int depot) {
  const float NEGINF = -__builtin_inff();
  const float4* rowp = (const float4*)(GT + (size_t)row * NN);
  const float4* du4 = (const float4*)sdu;
  float fv = NEGINF;
  int fi = NN;
#pragma unroll
  for (int r = 0; r < 8; ++r) {
    float4 g4 = rowp[r * 64 + lane];
    float4 pA = du4[(r * 64 + lane) * 2];      // d0,u0,d1,u1
    float4 pB = du4[(r * 64 + lane) * 2 + 1];  // d2,u2,d3,u3
    float gl[4] = {g4.x, g4.y, g4.z, g4.w};
    float dl[4] = {pA.x, pA.z, pB.x, pB.z};
    float ul[4] = {pA.y, pA.w, pB.y, pB.w};
    float cv = NEGINF;
    int cj = 0;
#pragma unroll
    for (int j = 0; j < 4; ++j) {
      float tt = fmaf(ul[j], lr, gl[j]);
      bool feas = (dl[j] <= load);
      if (feas && tt > cv) { cv = tt; cj = j; }
    }
    if (cv > fv) { fv = cv; fi = 4 * (r * 64 + lane) + cj; }  // asc r: first-max
  }
  float bv = fv;
  int bi = fi;
  DPP_MERGE2(0x111); DPP_MERGE2(0x112); DPP_MERGE2(0x114);
  DPP_MERGE2(0x118); DPP_MERGE2(0x142); DPP_MERGE2(0x143);
  float fbv = __int_as_float(__builtin_amdgcn_readlane(__float_as_int(bv), 63));
  int fbi = __builtin_amdgcn_readlane(bi, 63);
  Pick p;
  p.take = (fbv > NEGINF) ? 1 : 0;
  p.nxt = p.take ? fbi : depot;
  return p;
}

// ---------------- sequential decode: ONE wave ------------------------------------
// Certified path: pure LDS+VALU, compact fallthrough. Fallbacks on demand.
__global__ __launch_bounds__(64, 1) void decode(const float* __restrict__ GT,
                                                const uint2* __restrict__ cand,
                                                const unsigned* __restrict__ pc16,
                                                const uint2* __restrict__ thrpk2,
                                                const float* __restrict__ u,
                                                const float* __restrict__ demands,
                                                const int* __restrict__ capp,
                                                const int* __restrict__ depotp,
                                                float* __restrict__ lrbuf,
                                                float* __restrict__ out) {
  __shared__ __align__(16) unsigned s_pc[NN * KL + 64];   // 123.1 KB packed lists
  __shared__ __align__(16) float2 s_du[NN];               // 16 KB (.x=d|+inf, .y=u)
  __shared__ __align__(16) uint2 s_thr[NN];               // 16 KB packed thresholds
  __shared__ __align__(16) unsigned short s_tour[TSTEPS + 2];  // 4.6 KB

  const int lane = threadIdx.x;
  const int depot = *depotp;
  const float capf = (float)(*capp);
  const float INF = __builtin_inff();
  const float C0 = 0.015625f;   // ALPHA / sqrt(HID), exact power of two
  const float MARGIN = 0.5f;    // >> any fp32 rounding in the bounds
  const float EGM = 0.0625f;    // > pack err 0.0156 + t-key trunc 0.0156 + rounding
  float* sduf = (float*)s_du;

  for (int i = lane; i < NN; i += 64) {
    s_du[i] = make_float2(demands[i], u[i]);
    s_thr[i] = thrpk2[i];
  }
  {
    const uint4* p4 = (const uint4*)pc16;
    uint4* q4 = (uint4*)s_pc;
    for (int i = lane; i < NN * KL / 4; i += 64) q4[i] = p4[i];
  }
  if (lane == 0) {
    sduf[2 * depot] = INF;  // depot starts visited
    s_tour[0] = (unsigned short)depot;
  }
  // single wave: per-wave LDS ordering suffices; no barrier needed

  int ntaken = 0, lasts = depot;
  float load = capf;
  float lr = load / capf;  // same fp32 division as reference
  int step = 0;
  const int lcl = (lane < KL) ? lane : (KL - 1);  // lanes >=15 duplicate entry 14

  for (; step < TSTEPS; ++step) {
    const int row = lasts;
    // ---- tier-1: 15 packed candidates, lanes 0-14 (pure LDS + VALU)
    unsigned pw = s_pc[row * KL + lcl];
    uint2 pk2 = s_thr[row];
    int i1x = (int)(pw & 0x7FFu);
    float2 du1 = s_du[i1x];              // dependent gather (ds_read_b64)
    float g1 = key2f(pw & 0xFFFFF800u);  // ghat <= g <= ghat + 0.0156
    float t1 = fmaf(du1.y, lr, g1);
    bool act = (lane < KL) && (du1.x <= load);
    unsigned m1 = act ? ((f2key(t1) & 0xFFFFF800u) | ((~(unsigned)i1x) & 0x7FFu)) : 0u;
    unsigned m2 = 0u;
    KRED(0x111); KRED(0x112); KRED(0x114); KRED(0x118);
    unsigned rv1k = (unsigned)__builtin_amdgcn_readlane((int)m1, 15);
    unsigned rv2k = (unsigned)__builtin_amdgcn_readlane((int)m2, 15);
    float rv1f = key2f(rv1k & 0xFFFFF800u);  // round-down: lower bd of winner t
    float rv2f = key2f(rv2k | 0x7FFu);       // round-up: upper bd of runner-up
    float t15 = __uint_as_float(pk2.x & 0xFFFF0000u);
    float m15 = __uint_as_float(pk2.x << 16);
    float B1 = fmaf(1.0f - lr, t15, lr * m15) + MARGIN;  // convex outside bound
    int take, nxt;
    if (__builtin_expect((rv1f > B1) && (rv1f > rv2f + EGM), 1)) {
      // certified: true t_w >= rv1f; rv1f > rv2f+EGM beats every other
      // in-list true t (trunc+pack err < EGM); rv1f > B1 beats every outside
      // node at this lr. Unique argmax == ref's pick. (No feasible cand ->
      // rv1k==0 -> rv1f NaN -> both compares false -> fallback.)
      take = 1;
      nxt = (int)((~rv1k) & 0x7FFu);
    } else {
      // ---- tier-2: on-demand exact eval of the 128-candidate list
      uint4 cc = ((const uint4*)(cand + (size_t)row * KCAND))[lane];
      float bv = -INF;
      int bi = 0x7fffffff;
      {
        float ga = __uint_as_float(cc.x); int ia = (int)cc.y;
        float gb = __uint_as_float(cc.z); int ib = (int)cc.w;
        float2 da = s_du[ia];
        float2 db = s_du[ib];
        float ta = fmaf(da.y, lr, ga);
        float tb = fmaf(db.y, lr, gb);
        if ((da.x <= load) && (ta > bv || (ta == bv && ia < bi))) { bv = ta; bi = ia; }
        if ((db.x <= load) && (tb > bv || (tb == bv && ib < bi))) { bv = tb; bi = ib; }
      }
      DPP_MERGE2(0x111); DPP_MERGE2(0x112); DPP_MERGE2(0x114);
      DPP_MERGE2(0x118); DPP_MERGE2(0x142); DPP_MERGE2(0x143);
      float rbv = __int_as_float(__builtin_amdgcn_readlane(__float_as_int(bv), 63));
      int rbi = __builtin_amdgcn_readlane(bi, 63);
      float t128 = __uint_as_float(pk2.y & 0xFFFF0000u);
      float m128 = __uint_as_float(pk2.y << 16);
      float B2 = fmaf(1.0f - lr, t128, lr * m128) + MARGIN;
      if (rbv > B2) {
        take = 1; nxt = rbi;
      } else {
        Pick p = tier3_scan(GT, (const float2*)s_du, row, lane, load, lr, depot);
        take = p.take; nxt = p.nxt;
      }
    }

    // ---- state update + output stores (identical fp ops to ref)
    if (lane == 0) {
      s_tour[1 + step] = (unsigned short)nxt;
      lrbuf[step] = take ? lr : -1.0f;  // fire-and-forget global store
    }
    if (take) {
      float dwin = s_du[nxt].x;  // raw demand (read BEFORE the INF mark below)
      load = load - dwin;        // same fp op sequence as reference
      ntaken++;
      if (lane == 0) sduf[2 * nxt] = INF;
    } else {
      load = capf;
      if (ntaken == NN - 1) { ++step; break; }  // done: ref emits (depot,0) on
    }
    lasts = nxt;
    lr = load / capf;  // same fp32 division as reference
  }

  // ref emits (depot, 0) forever once done
  for (int q = step + lane; q < TSTEPS; q += 64) {
    s_tour[1 + q] = (unsigned short)depot;
    lrbuf[q] = -1.0f;
  }
  // drain all outstanding global stores (lrbuf) before reading them back
  asm volatile("s_waitcnt vmcnt(0)" ::: "memory");
  // ---- flush tour; compute scores exactly in a parallel deferred pass
  for (int i = lane; i <= TSTEPS; i += 64) out[i] = (float)s_tour[i];
  for (int s = lane; s < TSTEPS; s += 64) {
    float lrs = lrbuf[s];
    float sc = 0.0f;
    if (lrs >= 0.0f) {
      int lastI = (int)s_tour[s];
      int biI = (int)s_tour[s + 1];
      float g = GT[(size_t)lastI * NN + biI];
      sc = fmaf(s_du[biI].y, lrs, g) * C0;  // identical expression to R3-R12
    }
    out[1 + TSTEPS + s] = sc;
  }
}

extern "C" void kernel_launch(void* const* d_in, const int* in_sizes, int n_in,
                              void* d_out, int out_size, void* d_ws, size_t ws_size,
                              hipStream_t stream) {
  const float* emb     = (const float*)d_in[0];  // [N, H]
  const float* demands = (const float*)d_in[1];  // [N]
  const float* Wq      = (const float*)d_in[2];  // [H, H+2]
  const float* bq      = (const float*)d_in[3];  // [H]
  const float* Wk      = (const float*)d_in[4];  // [H, H]
  const float* bk      = (const float*)d_in[5];  // [H]
  const int* cap       = (const int*)d_in[6];
  const int* depot     = (const int*)d_in[7];
  float* out           = (float*)d_out;          // 2305 tour + 2304 scores, fp32

  char* ws = (char*)d_ws;
  float* Kmat = (float*)(ws);                         // 8 MB  [N,H]
  float* Z    = (float*)(ws + ((size_t)8 << 20));     // 8 MB  [N,H]
  float* GT   = (float*)(ws + ((size_t)16 << 20));    // 16 MB [N,N] row=last, +v
  float* Wqh  = (float*)(ws + ((size_t)32 << 20));    // 4 MB  [H,H]; later overlaid
  float* u    = (float*)(ws + ((size_t)36 << 20));    // 8 KB
  float* v    = (float*)(ws + ((size_t)36 << 20) + 8192);
  float* sink = (float*)(ws + ((size_t)36 << 20) + 32768);  // warm sink (unused)
  // overlays of the dead Wqh region (Wqh dead after the Z GEMM):
  uint2* cnd  = (uint2*)Wqh;                                        // 2 MB
  unsigned* pc16g = (unsigned*)(ws + ((size_t)34 << 20));           // 120 KB
  uint2* thrpk2g  = (uint2*)(ws + ((size_t)34 << 20) + (128 << 10)); // 16 KB
  float* lrbuf    = (float*)(ws + ((size_t)34 << 20) + (160 << 10)); // 9.2 KB

  hipLaunchKernelGGL(prep_wqh, dim3(4096), dim3(256), 0, stream, Wq, Wqh);
  // K = emb @ Wk^T + bk
  hipLaunchKernelGGL(gemm_nt, dim3(HH / TILE, NN / TILE), dim3(256), 0, stream,
                     emb, HH, Wk, HH, Kmat, HH, HH, bk);
  // Z = emb @ Wqh^T
  hipLaunchKernelGGL(gemm_nt, dim3(HH / TILE, NN / TILE), dim3(256), 0, stream,
                     emb, HH, Wqh, HH, Z, HH, HH, (const float*)nullptr);
  // u_i = K_i . Wq[:,H], v_i = K_i . bq
  hipLaunchKernelGGL(uv_k, dim3(NN), dim3(64), 0, stream, Kmat, Wq, bq, u, v);
  // GT = Z @ K^T + v (v==0 since bq==0 -> bit-identical)
  hipLaunchKernelGGL(gemm_nt, dim3(NN / TILE, NN / TILE), dim3(256), 0, stream,
                     Z, HH, Kmat, HH, GT, NN, HH, v);
  // top-128 lists + packed top-15 + convex-bound thresholds (overlay dead Wqh)
  hipLaunchKernelGGL(prep_cand, dim3(NN), dim3(256), 0, stream, GT, u, cnd,
                     pc16g, thrpk2g);
  // pre-warm LLC with cand (2 MB) + pc16/thr for the on-demand fallbacks
  hipLaunchKernelGGL(warm_k, dim3(128), dim3(256), 0, stream,
                     (const float*)cnd, NN * KCAND * 2 + (160 << 8), sink);
  hipLaunchKernelGGL(decode, dim3(1), dim3(64), 0, stream, GT, cnd,
                     pc16g, thrpk2g, u, demands, cap, depot, lrbuf, out);
}